// Round 14
// baseline (1680.966 us; speedup 1.0000x reference)
//
#include <hip/hip_runtime.h>

// HashEmbedding (Instant-NGP hash grid), MI355X gfx950.
// Round 14: counting sort (R11) + sorted gather at the TA issue wall
// (0.96 lane-transactions/cy/CU measured) + XOR-adjacency float4 pairing:
// corners (c,c+4) differ by v0->v0+1 = XOR 1 when v0 even -> one aligned
// 16B float4 covers both (1 lane-slot instead of 2). 8 slots/level -> ~6.

#define NLVL 16
#define TMASK ((1u << 19) - 1u)
#define P1 2654435761u
#define P2 805459861u
#define NBINS 32768         // 32 x 32 x 32

__constant__ float c_res[NLVL] = {16.f, 20.f, 25.f, 32.f, 40.f, 50.f, 64.f, 80.f,
                                  101.f, 128.f, 161.f, 203.f, 256.f, 322.f, 406.f, 512.f};

__device__ __forceinline__ int bin_of(float xn0, float xn1, float xn2)
{
    int bx = (int)((xn0 - 0.5f) * 64.f);
    int by = (int)((xn1 - 0.5f) * 64.f);
    int bz = (int)((xn2 - 0.5f) * 64.f);
    bx = bx < 0 ? 0 : (bx > 31 ? 31 : bx);
    by = by < 0 ? 0 : (by > 31 ? 31 : by);
    bz = bz < 0 ? 0 : (bz > 31 ? 31 : bz);
    return (bx << 10) | (by << 5) | bz;
}

__device__ __forceinline__ void corner_idx(float xn0, float xn1, float xn2, float r,
                                           unsigned idx[8], float& w0, float& w1, float& w2)
{
    const float s0 = xn0 * r;
    const float s1 = xn1 * r;
    const float s2 = xn2 * r;
    const float f0 = floorf(s0);
    const float f1 = floorf(s1);
    const float f2 = floorf(s2);
    w0 = s0 - f0;
    w1 = s1 - f1;
    w2 = s2 - f2;
    const unsigned v0 = (unsigned)(int)f0;
    const unsigned v1 = (unsigned)(int)f1;
    const unsigned v2 = (unsigned)(int)f2;

    const unsigned ax0 = v0;
    const unsigned ax1 = v0 + 1u;
    const unsigned bx0 = v1 * P1;
    const unsigned bx1 = (v1 + 1u) * P1;
    const unsigned cx0 = v2 * P2;
    const unsigned cx1 = (v2 + 1u) * P2;

    idx[0] = (ax0 ^ bx0 ^ cx0) & TMASK;
    idx[1] = (ax0 ^ bx0 ^ cx1) & TMASK;
    idx[2] = (ax0 ^ bx1 ^ cx0) & TMASK;
    idx[3] = (ax0 ^ bx1 ^ cx1) & TMASK;
    idx[4] = (ax1 ^ bx0 ^ cx0) & TMASK;
    idx[5] = (ax1 ^ bx0 ^ cx1) & TMASK;
    idx[6] = (ax1 ^ bx1 ^ cx0) & TMASK;
    idx[7] = (ax1 ^ bx1 ^ cx1) & TMASK;
}

__device__ __forceinline__ float2 sel_half(const float4 v, unsigned odd)
{
    return odd ? make_float2(v.z, v.w) : make_float2(v.x, v.y);
}

__device__ __forceinline__ float2 trilerp(const float2 e[8], float w0, float w1, float w2)
{
    const float omx = 1.0f - w0;
    const float omy = 1.0f - w1;
    const float omz = 1.0f - w2;

    const float c00x = e[0].x * omx + e[4].x * w0;
    const float c00y = e[0].y * omx + e[4].y * w0;
    const float c01x = e[1].x * omx + e[5].x * w0;
    const float c01y = e[1].y * omx + e[5].y * w0;
    const float c10x = e[2].x * omx + e[6].x * w0;
    const float c10y = e[2].y * omx + e[6].y * w0;
    const float c11x = e[3].x * omx + e[7].x * w0;
    const float c11y = e[3].y * omx + e[7].y * w0;

    const float c0x = c00x * omy + c10x * w1;
    const float c0y = c00y * omy + c10y * w1;
    const float c1x = c01x * omy + c11x * w1;
    const float c1y = c01y * omy + c11y * w1;

    float2 o;
    o.x = c0x * omz + c1x * w2;
    o.y = c0y * omz + c1y * w2;
    return o;
}

// ---- Pass 1: count points per bin ----
__global__ __launch_bounds__(256)
void k_count(const float* __restrict__ x, unsigned* __restrict__ counts)
{
    const int p = blockIdx.x * 256 + threadIdx.x;
    const float xn0 = (x[3 * p + 0] + 1.0f) * 0.5f;
    const float xn1 = (x[3 * p + 1] + 1.0f) * 0.5f;
    const float xn2 = (x[3 * p + 2] + 1.0f) * 0.5f;
    atomicAdd(&counts[bin_of(xn0, xn1, xn2)], 1u);
}

// ---- Pass 2: exclusive scan of counts -> cursor (mutable bases) ----
__global__ __launch_bounds__(1024)
void k_scan(const unsigned* __restrict__ counts, unsigned* __restrict__ cursor)
{
    __shared__ unsigned s[1024];
    const int t = threadIdx.x;
    unsigned loc[32];
    unsigned sum = 0;
#pragma unroll
    for (int i = 0; i < 32; ++i) {
        loc[i] = sum;
        sum += counts[t * 32 + i];
    }
    s[t] = sum;
    __syncthreads();
    for (int off = 1; off < 1024; off <<= 1) {
        const unsigned v = (t >= off) ? s[t - off] : 0u;
        __syncthreads();
        s[t] += v;
        __syncthreads();
    }
    const unsigned blockbase = (t > 0) ? s[t - 1] : 0u;
#pragma unroll
    for (int i = 0; i < 32; ++i)
        cursor[t * 32 + i] = blockbase + loc[i];
}

// ---- Pass 3: place points in bin-sorted order ----
__global__ __launch_bounds__(256)
void k_place(const float* __restrict__ x,
             unsigned* __restrict__ cursor,
             float4* __restrict__ sorted_pts)
{
    const int p = blockIdx.x * 256 + threadIdx.x;
    const float xn0 = (x[3 * p + 0] + 1.0f) * 0.5f;
    const float xn1 = (x[3 * p + 1] + 1.0f) * 0.5f;
    const float xn2 = (x[3 * p + 2] + 1.0f) * 0.5f;
    const unsigned pos = atomicAdd(&cursor[bin_of(xn0, xn1, xn2)], 1u);
    float4 e;
    e.x = xn0; e.y = xn1; e.z = xn2; e.w = __uint_as_float((unsigned)p);
    sorted_pts[pos] = e;
}

// ---- Pass 4: sorted gather with XOR-paired float4 loads ----
__global__ __launch_bounds__(256, 4)
void k_gather_sorted(const float4* __restrict__ sorted_pts,
                     const float* __restrict__ tables,
                     float* __restrict__ out)
{
    const unsigned bid = blockIdx.x;
    const unsigned newbid = (bid & 7u) * 512u + (bid >> 3);
    const int sp = (int)(newbid * 256u + threadIdx.x);

    const float4 e = sorted_pts[sp];
    const float xn0 = e.x, xn1 = e.y, xn2 = e.z;
    const unsigned pidx = __float_as_uint(e.w);

    float o[2 * NLVL];
#pragma unroll
    for (int l = 0; l < NLVL; ++l) {
        const float2* __restrict__ tab = (const float2*)tables + ((size_t)l << 19);
        unsigned idx[8];
        float w0, w1, w2;
        corner_idx(xn0, xn1, xn2, c_res[l], idx, w0, w1, w2);

        // paired loads: float4 at (idx[c] & ~1) covers corners c and c+4
        // whenever idx[c+4] == idx[c]^1 (v0 even, ~50% of lanes)
        float4 f[4];
#pragma unroll
        for (int c = 0; c < 4; ++c)
            f[c] = *reinterpret_cast<const float4*>(tab + (idx[c] & ~1u));

        float2 ee[8];
#pragma unroll
        for (int c = 0; c < 4; ++c) {
            ee[c]     = sel_half(f[c], idx[c] & 1u);
            ee[c + 4] = sel_half(f[c], idx[c + 4] & 1u);
        }
        // masked fixups for odd-v0 lanes
#pragma unroll
        for (int c = 0; c < 4; ++c)
            if (idx[c + 4] != (idx[c] ^ 1u)) ee[c + 4] = tab[idx[c + 4]];

        const float2 v = trilerp(ee, w0, w1, w2);
        o[2 * l + 0] = v.x;
        o[2 * l + 1] = v.y;
    }

    float4* op = (float4*)(out + (size_t)pidx * 32);
#pragma unroll
    for (int q = 0; q < 8; ++q)
        op[q] = make_float4(o[4 * q], o[4 * q + 1], o[4 * q + 2], o[4 * q + 3]);
}

// ---- Fallback: single-kernel f32 version (unexpected n or small ws) ----
__global__ __launch_bounds__(256)
void hash_embed_fallback(const float* __restrict__ x,
                         const float* __restrict__ tables,
                         float* __restrict__ out,
                         int n)
{
    const int p = blockIdx.x * 256 + threadIdx.x;
    if (p >= n) return;

    const float xn0 = (x[3 * p + 0] + 1.0f) * 0.5f;
    const float xn1 = (x[3 * p + 1] + 1.0f) * 0.5f;
    const float xn2 = (x[3 * p + 2] + 1.0f) * 0.5f;

    float o[2 * NLVL];
#pragma unroll
    for (int l = 0; l < NLVL; ++l) {
        const float2* tab = (const float2*)tables + ((size_t)l << 19);
        unsigned idx[8];
        float w0, w1, w2;
        corner_idx(xn0, xn1, xn2, c_res[l], idx, w0, w1, w2);
        float2 ee[8];
#pragma unroll
        for (int c = 0; c < 8; ++c) ee[c] = tab[idx[c]];
        const float2 v = trilerp(ee, w0, w1, w2);
        o[2 * l + 0] = v.x;
        o[2 * l + 1] = v.y;
    }

    float4* op = (float4*)(out + (size_t)p * 32);
#pragma unroll
    for (int q = 0; q < 8; ++q)
        op[q] = make_float4(o[4 * q], o[4 * q + 1], o[4 * q + 2], o[4 * q + 3]);
}

extern "C" void kernel_launch(void* const* d_in, const int* in_sizes, int n_in,
                              void* d_out, int out_size, void* d_ws, size_t ws_size,
                              hipStream_t stream) {
    const float* x = (const float*)d_in[0];
    const float* tables = (const float*)d_in[1];
    float* out = (float*)d_out;
    const int n = in_sizes[0] / 3;                       // 1048576

    char* ws = (char*)d_ws;
    float4*   sorted_pts = (float4*)ws;                                   // 16 MB
    unsigned* counts     = (unsigned*)(ws + ((size_t)16 << 20));          // 128 KB
    unsigned* cursor     = (unsigned*)(ws + ((size_t)16 << 20) + (128 << 10)); // 128 KB
    const size_t ws_needed = ((size_t)16 << 20) + (256 << 10);

    if (n == (1 << 20) && ws_size >= ws_needed) {
        hipMemsetAsync(counts, 0, NBINS * sizeof(unsigned), stream);
        k_count<<<4096, 256, 0, stream>>>(x, counts);
        k_scan<<<1, 1024, 0, stream>>>(counts, cursor);
        k_place<<<4096, 256, 0, stream>>>(x, cursor, sorted_pts);
        k_gather_sorted<<<4096, 256, 0, stream>>>(sorted_pts, tables, out);
    } else {
        hash_embed_fallback<<<(n + 255) / 256, 256, 0, stream>>>(x, tables, out, n);
    }
}

// Round 15
// 1663.818 us; speedup vs baseline: 1.0103x; 1.0103x over previous
//
#include <hip/hip_runtime.h>

// HashEmbedding (Instant-NGP hash grid), MI355X gfx950.
// Round 15: R13 base (counting sort + sorted gather + XCD chunk) with
// XOR-adjacency float4 pairing, SPILL-PROOF: all divergently-written values
// are named scalars (no local-array writes under divergence -> no scratch
// demotion, cf. R14's 2.3GB spill round-trip). Corners (c,c+4) share one
// aligned 16B float4 when v0 is even (~50% lanes); odd-v0 lanes take an
// exec-masked fixup load. 8 gather slots/level -> ~6.

#define NLVL 16
#define TMASK ((1u << 19) - 1u)
#define P1 2654435761u
#define P2 805459861u
#define NBINS 32768         // 32 x 32 x 32

__constant__ float c_res[NLVL] = {16.f, 20.f, 25.f, 32.f, 40.f, 50.f, 64.f, 80.f,
                                  101.f, 128.f, 161.f, 203.f, 256.f, 322.f, 406.f, 512.f};

__device__ __forceinline__ int bin_of(float xn0, float xn1, float xn2)
{
    int bx = (int)((xn0 - 0.5f) * 64.f);
    int by = (int)((xn1 - 0.5f) * 64.f);
    int bz = (int)((xn2 - 0.5f) * 64.f);
    bx = bx < 0 ? 0 : (bx > 31 ? 31 : bx);
    by = by < 0 ? 0 : (by > 31 ? 31 : by);
    bz = bz < 0 ? 0 : (bz > 31 ? 31 : bz);
    return (bx << 10) | (by << 5) | bz;
}

__device__ __forceinline__ float2 sel_half(const float4 v, unsigned odd)
{
    return odd ? make_float2(v.z, v.w) : make_float2(v.x, v.y);
}

// ---- Pass 1: count points per bin ----
__global__ __launch_bounds__(256)
void k_count(const float* __restrict__ x, unsigned* __restrict__ counts)
{
    const int p = blockIdx.x * 256 + threadIdx.x;
    const float xn0 = (x[3 * p + 0] + 1.0f) * 0.5f;
    const float xn1 = (x[3 * p + 1] + 1.0f) * 0.5f;
    const float xn2 = (x[3 * p + 2] + 1.0f) * 0.5f;
    atomicAdd(&counts[bin_of(xn0, xn1, xn2)], 1u);
}

// ---- Pass 2: exclusive scan of counts -> cursor (mutable bases) ----
__global__ __launch_bounds__(1024)
void k_scan(const unsigned* __restrict__ counts, unsigned* __restrict__ cursor)
{
    __shared__ unsigned s[1024];
    const int t = threadIdx.x;
    unsigned loc[32];
    unsigned sum = 0;
#pragma unroll
    for (int i = 0; i < 32; ++i) {
        loc[i] = sum;
        sum += counts[t * 32 + i];
    }
    s[t] = sum;
    __syncthreads();
    for (int off = 1; off < 1024; off <<= 1) {
        const unsigned v = (t >= off) ? s[t - off] : 0u;
        __syncthreads();
        s[t] += v;
        __syncthreads();
    }
    const unsigned blockbase = (t > 0) ? s[t - 1] : 0u;
#pragma unroll
    for (int i = 0; i < 32; ++i)
        cursor[t * 32 + i] = blockbase + loc[i];
}

// ---- Pass 3: place points in bin-sorted order ----
__global__ __launch_bounds__(256)
void k_place(const float* __restrict__ x,
             unsigned* __restrict__ cursor,
             float4* __restrict__ sorted_pts)
{
    const int p = blockIdx.x * 256 + threadIdx.x;
    const float xn0 = (x[3 * p + 0] + 1.0f) * 0.5f;
    const float xn1 = (x[3 * p + 1] + 1.0f) * 0.5f;
    const float xn2 = (x[3 * p + 2] + 1.0f) * 0.5f;
    const unsigned pos = atomicAdd(&cursor[bin_of(xn0, xn1, xn2)], 1u);
    float4 e;
    e.x = xn0; e.y = xn1; e.z = xn2; e.w = __uint_as_float((unsigned)p);
    sorted_pts[pos] = e;
}

// ---- Pass 4: sorted gather, XOR-paired loads, scalar-only divergent writes ----
__global__ __launch_bounds__(256, 4)
void k_gather_sorted(const float4* __restrict__ sorted_pts,
                     const float* __restrict__ tables,
                     float* __restrict__ out)
{
    const unsigned bid = blockIdx.x;
    const unsigned newbid = (bid & 7u) * 512u + (bid >> 3);
    const int sp = (int)(newbid * 256u + threadIdx.x);

    const float4 e = sorted_pts[sp];
    const float xn0 = e.x, xn1 = e.y, xn2 = e.z;
    const unsigned pidx = __float_as_uint(e.w);

    float o[2 * NLVL];
#pragma unroll
    for (int l = 0; l < NLVL; ++l) {
        const float2* __restrict__ tab = (const float2*)tables + ((size_t)l << 19);
        const float r = c_res[l];

        const float s0 = xn0 * r, s1 = xn1 * r, s2 = xn2 * r;
        const float f0 = floorf(s0), f1 = floorf(s1), f2 = floorf(s2);
        const float w0 = s0 - f0, w1 = s1 - f1, w2 = s2 - f2;
        const unsigned v0 = (unsigned)(int)f0;
        const unsigned v1 = (unsigned)(int)f1;
        const unsigned v2 = (unsigned)(int)f2;

        const unsigned bx0 = v1 * P1;
        const unsigned bx1 = (v1 + 1u) * P1;
        const unsigned cx0 = v2 * P2;
        const unsigned cx1 = (v2 + 1u) * P2;

        const unsigned i0 = (v0 ^ bx0 ^ cx0) & TMASK;          // corner (0,0,0)
        const unsigned i1 = (v0 ^ bx0 ^ cx1) & TMASK;          // (0,0,1)
        const unsigned i2 = (v0 ^ bx1 ^ cx0) & TMASK;          // (0,1,0)
        const unsigned i3 = (v0 ^ bx1 ^ cx1) & TMASK;          // (0,1,1)
        const unsigned j0 = ((v0 + 1u) ^ bx0 ^ cx0) & TMASK;   // (1,0,0)
        const unsigned j1 = ((v0 + 1u) ^ bx0 ^ cx1) & TMASK;   // (1,0,1)
        const unsigned j2 = ((v0 + 1u) ^ bx1 ^ cx0) & TMASK;   // (1,1,0)
        const unsigned j3 = ((v0 + 1u) ^ bx1 ^ cx1) & TMASK;   // (1,1,1)

        // paired 16B loads cover (i_c, j_c) when v0 even (j_c == i_c^1)
        const float4 fA = *reinterpret_cast<const float4*>(tab + (i0 & ~1u));
        const float4 fB = *reinterpret_cast<const float4*>(tab + (i1 & ~1u));
        const float4 fC = *reinterpret_cast<const float4*>(tab + (i2 & ~1u));
        const float4 fD = *reinterpret_cast<const float4*>(tab + (i3 & ~1u));

        float2 e0 = sel_half(fA, i0 & 1u);
        float2 e1 = sel_half(fB, i1 & 1u);
        float2 e2 = sel_half(fC, i2 & 1u);
        float2 e3 = sel_half(fD, i3 & 1u);
        float2 e4 = sel_half(fA, j0 & 1u);
        float2 e5 = sel_half(fB, j1 & 1u);
        float2 e6 = sel_half(fC, j2 & 1u);
        float2 e7 = sel_half(fD, j3 & 1u);

        // exec-masked fixups for odd-v0 lanes (scalar writes only)
        const bool odd = (v0 & 1u) != 0u;
        if (odd) e4 = tab[j0];
        if (odd) e5 = tab[j1];
        if (odd) e6 = tab[j2];
        if (odd) e7 = tab[j3];

        const float omx = 1.0f - w0, omy = 1.0f - w1, omz = 1.0f - w2;
        const float c00x = e0.x * omx + e4.x * w0;
        const float c00y = e0.y * omx + e4.y * w0;
        const float c01x = e1.x * omx + e5.x * w0;
        const float c01y = e1.y * omx + e5.y * w0;
        const float c10x = e2.x * omx + e6.x * w0;
        const float c10y = e2.y * omx + e6.y * w0;
        const float c11x = e3.x * omx + e7.x * w0;
        const float c11y = e3.y * omx + e7.y * w0;
        const float c0x = c00x * omy + c10x * w1;
        const float c0y = c00y * omy + c10y * w1;
        const float c1x = c01x * omy + c11x * w1;
        const float c1y = c01y * omy + c11y * w1;
        o[2 * l + 0] = c0x * omz + c1x * w2;
        o[2 * l + 1] = c0y * omz + c1y * w2;
    }

    float4* op = (float4*)(out + (size_t)pidx * 32);
#pragma unroll
    for (int q = 0; q < 8; ++q)
        op[q] = make_float4(o[4 * q], o[4 * q + 1], o[4 * q + 2], o[4 * q + 3]);
}

// ---- Fallback: single-kernel f32 version (unexpected n or small ws) ----
__global__ __launch_bounds__(256)
void hash_embed_fallback(const float* __restrict__ x,
                         const float* __restrict__ tables,
                         float* __restrict__ out,
                         int n)
{
    const int p = blockIdx.x * 256 + threadIdx.x;
    if (p >= n) return;

    const float xn0 = (x[3 * p + 0] + 1.0f) * 0.5f;
    const float xn1 = (x[3 * p + 1] + 1.0f) * 0.5f;
    const float xn2 = (x[3 * p + 2] + 1.0f) * 0.5f;

    float o[2 * NLVL];
#pragma unroll
    for (int l = 0; l < NLVL; ++l) {
        const float2* tab = (const float2*)tables + ((size_t)l << 19);
        const float r = c_res[l];
        const float s0 = xn0 * r, s1 = xn1 * r, s2 = xn2 * r;
        const float f0 = floorf(s0), f1 = floorf(s1), f2 = floorf(s2);
        const float w0 = s0 - f0, w1 = s1 - f1, w2 = s2 - f2;
        const unsigned v0 = (unsigned)(int)f0;
        const unsigned v1 = (unsigned)(int)f1;
        const unsigned v2 = (unsigned)(int)f2;
        const unsigned bx0 = v1 * P1, bx1 = (v1 + 1u) * P1;
        const unsigned cx0 = v2 * P2, cx1 = (v2 + 1u) * P2;
        const float2 e0 = tab[(v0 ^ bx0 ^ cx0) & TMASK];
        const float2 e1 = tab[(v0 ^ bx0 ^ cx1) & TMASK];
        const float2 e2 = tab[(v0 ^ bx1 ^ cx0) & TMASK];
        const float2 e3 = tab[(v0 ^ bx1 ^ cx1) & TMASK];
        const float2 e4 = tab[((v0 + 1u) ^ bx0 ^ cx0) & TMASK];
        const float2 e5 = tab[((v0 + 1u) ^ bx0 ^ cx1) & TMASK];
        const float2 e6 = tab[((v0 + 1u) ^ bx1 ^ cx0) & TMASK];
        const float2 e7 = tab[((v0 + 1u) ^ bx1 ^ cx1) & TMASK];
        const float omx = 1.f - w0, omy = 1.f - w1, omz = 1.f - w2;
        const float c00x = e0.x * omx + e4.x * w0;
        const float c00y = e0.y * omx + e4.y * w0;
        const float c01x = e1.x * omx + e5.x * w0;
        const float c01y = e1.y * omx + e5.y * w0;
        const float c10x = e2.x * omx + e6.x * w0;
        const float c10y = e2.y * omx + e6.y * w0;
        const float c11x = e3.x * omx + e7.x * w0;
        const float c11y = e3.y * omx + e7.y * w0;
        const float c0x = c00x * omy + c10x * w1;
        const float c0y = c00y * omy + c10y * w1;
        const float c1x = c01x * omy + c11x * w1;
        const float c1y = c01y * omy + c11y * w1;
        o[2 * l + 0] = c0x * omz + c1x * w2;
        o[2 * l + 1] = c0y * omz + c1y * w2;
    }

    float4* op = (float4*)(out + (size_t)p * 32);
#pragma unroll
    for (int q = 0; q < 8; ++q)
        op[q] = make_float4(o[4 * q], o[4 * q + 1], o[4 * q + 2], o[4 * q + 3]);
}

extern "C" void kernel_launch(void* const* d_in, const int* in_sizes, int n_in,
                              void* d_out, int out_size, void* d_ws, size_t ws_size,
                              hipStream_t stream) {
    const float* x = (const float*)d_in[0];
    const float* tables = (const float*)d_in[1];
    float* out = (float*)d_out;
    const int n = in_sizes[0] / 3;                       // 1048576

    char* ws = (char*)d_ws;
    float4*   sorted_pts = (float4*)ws;                                   // 16 MB
    unsigned* counts     = (unsigned*)(ws + ((size_t)16 << 20));          // 128 KB
    unsigned* cursor     = (unsigned*)(ws + ((size_t)16 << 20) + (128 << 10)); // 128 KB
    const size_t ws_needed = ((size_t)16 << 20) + (256 << 10);

    if (n == (1 << 20) && ws_size >= ws_needed) {
        hipMemsetAsync(counts, 0, NBINS * sizeof(unsigned), stream);
        k_count<<<4096, 256, 0, stream>>>(x, counts);
        k_scan<<<1, 1024, 0, stream>>>(counts, cursor);
        k_place<<<4096, 256, 0, stream>>>(x, cursor, sorted_pts);
        k_gather_sorted<<<4096, 256, 0, stream>>>(sorted_pts, tables, out);
    } else {
        hash_embed_fallback<<<(n + 255) / 256, 256, 0, stream>>>(x, tables, out, n);
    }
}

// Round 16
// 431.736 us; speedup vs baseline: 3.8935x; 3.8538x over previous
//
#include <hip/hip_runtime.h>

// HashEmbedding (Instant-NGP hash grid), MI355X gfx950.
// Round 16: counting sort (R11) + sorted gather with per-block LDS staging
// of coarse/mid levels. A 256-pt sorted block has a tiny bbox; levels whose
// block vertex-set fits a shared 2048-entry pool are gathered once per block
// into LDS (~1700 divergent lanes) instead of per-point (24576 lanes).
// Per-level block-uniform fallback to the proven direct path (s_base[l]<0).
// Global lane-slots/point: 128 -> ~40 (TA issue wall was 0.96 lanes/cy/CU).

#define NLVL 16
#define TMASK ((1u << 19) - 1u)
#define P1 2654435761u
#define P2 805459861u
#define NBINS 32768         // 32 x 32 x 32 spatial bins for the sort
#define NS 13               // levels 0..12 are staging candidates
#define CAP 2048            // LDS vertex pool entries (16 KB)

__constant__ float c_res[NLVL] = {16.f, 20.f, 25.f, 32.f, 40.f, 50.f, 64.f, 80.f,
                                  101.f, 128.f, 161.f, 203.f, 256.f, 322.f, 406.f, 512.f};

__device__ __forceinline__ int bin_of(float xn0, float xn1, float xn2)
{
    int bx = (int)((xn0 - 0.5f) * 64.f);
    int by = (int)((xn1 - 0.5f) * 64.f);
    int bz = (int)((xn2 - 0.5f) * 64.f);
    bx = bx < 0 ? 0 : (bx > 31 ? 31 : bx);
    by = by < 0 ? 0 : (by > 31 ? 31 : by);
    bz = bz < 0 ? 0 : (bz > 31 ? 31 : bz);
    return (bx << 10) | (by << 5) | bz;
}

// ---- Pass 1: count points per bin ----
__global__ __launch_bounds__(256)
void k_count(const float* __restrict__ x, unsigned* __restrict__ counts)
{
    const int p = blockIdx.x * 256 + threadIdx.x;
    const float xn0 = (x[3 * p + 0] + 1.0f) * 0.5f;
    const float xn1 = (x[3 * p + 1] + 1.0f) * 0.5f;
    const float xn2 = (x[3 * p + 2] + 1.0f) * 0.5f;
    atomicAdd(&counts[bin_of(xn0, xn1, xn2)], 1u);
}

// ---- Pass 2: exclusive scan of counts -> cursor ----
__global__ __launch_bounds__(1024)
void k_scan(const unsigned* __restrict__ counts, unsigned* __restrict__ cursor)
{
    __shared__ unsigned s[1024];
    const int t = threadIdx.x;
    unsigned loc[32];
    unsigned sum = 0;
#pragma unroll
    for (int i = 0; i < 32; ++i) {
        loc[i] = sum;
        sum += counts[t * 32 + i];
    }
    s[t] = sum;
    __syncthreads();
    for (int off = 1; off < 1024; off <<= 1) {
        const unsigned v = (t >= off) ? s[t - off] : 0u;
        __syncthreads();
        s[t] += v;
        __syncthreads();
    }
    const unsigned blockbase = (t > 0) ? s[t - 1] : 0u;
#pragma unroll
    for (int i = 0; i < 32; ++i)
        cursor[t * 32 + i] = blockbase + loc[i];
}

// ---- Pass 3: place points in bin-sorted order ----
__global__ __launch_bounds__(256)
void k_place(const float* __restrict__ x,
             unsigned* __restrict__ cursor,
             float4* __restrict__ sorted_pts)
{
    const int p = blockIdx.x * 256 + threadIdx.x;
    const float xn0 = (x[3 * p + 0] + 1.0f) * 0.5f;
    const float xn1 = (x[3 * p + 1] + 1.0f) * 0.5f;
    const float xn2 = (x[3 * p + 2] + 1.0f) * 0.5f;
    const unsigned pos = atomicAdd(&cursor[bin_of(xn0, xn1, xn2)], 1u);
    float4 e;
    e.x = xn0; e.y = xn1; e.z = xn2; e.w = __uint_as_float((unsigned)p);
    sorted_pts[pos] = e;
}

// ---- Pass 4: sorted gather with per-block LDS vertex staging ----
__global__ __launch_bounds__(256)
void k_gather_staged(const float4* __restrict__ sorted_pts,
                     const float* __restrict__ tables,
                     float* __restrict__ out)
{
    __shared__ float2 s_tab[CAP];      // 16 KB vertex pool
    __shared__ int    s_base[NS];      // staged level base offsets (-1 = direct)
    __shared__ float  s_bb[4][6];      // per-wave bbox partials

    const int t = threadIdx.x;
    const int sp = blockIdx.x * 256 + t;

    const float4 e = sorted_pts[sp];
    const float xn0 = e.x, xn1 = e.y, xn2 = e.z;
    const unsigned pidx = __float_as_uint(e.w);

    // ---- block bbox (wave shfl reduce, then cross-wave via LDS) ----
    float mnx = xn0, mxx = xn0, mny = xn1, mxy = xn1, mnz = xn2, mxz = xn2;
#pragma unroll
    for (int off = 32; off; off >>= 1) {
        mnx = fminf(mnx, __shfl_xor(mnx, off));
        mxx = fmaxf(mxx, __shfl_xor(mxx, off));
        mny = fminf(mny, __shfl_xor(mny, off));
        mxy = fmaxf(mxy, __shfl_xor(mxy, off));
        mnz = fminf(mnz, __shfl_xor(mnz, off));
        mxz = fmaxf(mxz, __shfl_xor(mxz, off));
    }
    if ((t & 63) == 0) {
        const int w = t >> 6;
        s_bb[w][0] = mnx; s_bb[w][1] = mxx; s_bb[w][2] = mny;
        s_bb[w][3] = mxy; s_bb[w][4] = mnz; s_bb[w][5] = mxz;
    }
    __syncthreads();
    mnx = fminf(fminf(s_bb[0][0], s_bb[1][0]), fminf(s_bb[2][0], s_bb[3][0]));
    mxx = fmaxf(fmaxf(s_bb[0][1], s_bb[1][1]), fmaxf(s_bb[2][1], s_bb[3][1]));
    mny = fminf(fminf(s_bb[0][2], s_bb[1][2]), fminf(s_bb[2][2], s_bb[3][2]));
    mxy = fmaxf(fmaxf(s_bb[0][3], s_bb[1][3]), fmaxf(s_bb[2][3], s_bb[3][3]));
    mnz = fminf(fminf(s_bb[0][4], s_bb[1][4]), fminf(s_bb[2][4], s_bb[3][4]));
    mxz = fmaxf(fmaxf(s_bb[0][5], s_bb[1][5]), fmaxf(s_bb[2][5], s_bb[3][5]));

    // ---- stage levels while they fit (sequential per level, no clustering) ----
    int cum = 0;
    for (int l = 0; l < NS; ++l) {
        const float r = c_res[l];
        const int v0lo = (int)floorf(mnx * r);
        const int v1lo = (int)floorf(mny * r);
        const int v2lo = (int)floorf(mnz * r);
        const int sx  = (int)floorf(mxx * r) + 2 - v0lo;
        const int sy  = (int)floorf(mxy * r) + 2 - v1lo;
        const int sz2 = (int)floorf(mxz * r) + 2 - v2lo;
        const int V = sx * sy * sz2;
        const bool ok = (cum + V <= CAP);
        if (t == 0) s_base[l] = ok ? cum : -1;
        if (ok) {
            const float2* __restrict__ tab = (const float2*)tables + ((size_t)l << 19);
            const int syz = sy * sz2;
            for (int u = t; u < V; u += 256) {
                const int i = u / syz;
                const int rem = u - i * syz;
                const int j = rem / sz2;
                const int k = rem - j * sz2;
                const unsigned hh = ((unsigned)(v0lo + i)
                                   ^ (unsigned)(v1lo + j) * P1
                                   ^ (unsigned)(v2lo + k) * P2) & TMASK;
                s_tab[cum + u] = tab[hh];
            }
            cum += V;
        }
    }
    __syncthreads();

    // ---- per-point interpolation: LDS path for staged levels, direct else ----
    float o[2 * NLVL];
#pragma unroll
    for (int l = 0; l < NLVL; ++l) {
        const float r = c_res[l];
        const float s0 = xn0 * r, s1 = xn1 * r, s2 = xn2 * r;
        const float f0 = floorf(s0), f1 = floorf(s1), f2 = floorf(s2);
        const float w0 = s0 - f0, w1 = s1 - f1, w2 = s2 - f2;
        const unsigned v0 = (unsigned)(int)f0;
        const unsigned v1 = (unsigned)(int)f1;
        const unsigned v2 = (unsigned)(int)f2;

        float2 e0, e1, e2, e3, e4, e5, e6, e7;
        int base = -1;
        if (l < NS) base = s_base[l];
        if (base >= 0) {
            const int v0lo = (int)floorf(mnx * r);
            const int v1lo = (int)floorf(mny * r);
            const int v2lo = (int)floorf(mnz * r);
            const int sy  = (int)floorf(mxy * r) + 2 - v1lo;
            const int sz2 = (int)floorf(mxz * r) + 2 - v2lo;
            const int syz = sy * sz2;
            const int a = (int)v0 - v0lo;
            const int b = (int)v1 - v1lo;
            const int c2 = (int)v2 - v2lo;
            const int p000 = base + a * syz + b * sz2 + c2;
            e0 = s_tab[p000];
            e1 = s_tab[p000 + 1];
            e2 = s_tab[p000 + sz2];
            e3 = s_tab[p000 + sz2 + 1];
            e4 = s_tab[p000 + syz];
            e5 = s_tab[p000 + syz + 1];
            e6 = s_tab[p000 + syz + sz2];
            e7 = s_tab[p000 + syz + sz2 + 1];
        } else {
            const float2* __restrict__ tab = (const float2*)tables + ((size_t)l << 19);
            const unsigned bx0 = v1 * P1, bx1 = (v1 + 1u) * P1;
            const unsigned cx0 = v2 * P2, cx1 = (v2 + 1u) * P2;
            e0 = tab[(v0 ^ bx0 ^ cx0) & TMASK];
            e1 = tab[(v0 ^ bx0 ^ cx1) & TMASK];
            e2 = tab[(v0 ^ bx1 ^ cx0) & TMASK];
            e3 = tab[(v0 ^ bx1 ^ cx1) & TMASK];
            e4 = tab[((v0 + 1u) ^ bx0 ^ cx0) & TMASK];
            e5 = tab[((v0 + 1u) ^ bx0 ^ cx1) & TMASK];
            e6 = tab[((v0 + 1u) ^ bx1 ^ cx0) & TMASK];
            e7 = tab[((v0 + 1u) ^ bx1 ^ cx1) & TMASK];
        }

        const float omx = 1.0f - w0, omy = 1.0f - w1, omz = 1.0f - w2;
        const float c00x = e0.x * omx + e4.x * w0;
        const float c00y = e0.y * omx + e4.y * w0;
        const float c01x = e1.x * omx + e5.x * w0;
        const float c01y = e1.y * omx + e5.y * w0;
        const float c10x = e2.x * omx + e6.x * w0;
        const float c10y = e2.y * omx + e6.y * w0;
        const float c11x = e3.x * omx + e7.x * w0;
        const float c11y = e3.y * omx + e7.y * w0;
        const float c0x = c00x * omy + c10x * w1;
        const float c0y = c00y * omy + c10y * w1;
        const float c1x = c01x * omy + c11x * w1;
        const float c1y = c01y * omy + c11y * w1;
        o[2 * l + 0] = c0x * omz + c1x * w2;
        o[2 * l + 1] = c0y * omz + c1y * w2;
    }

    float4* op = (float4*)(out + (size_t)pidx * 32);
#pragma unroll
    for (int q = 0; q < 8; ++q)
        op[q] = make_float4(o[4 * q], o[4 * q + 1], o[4 * q + 2], o[4 * q + 3]);
}

// ---- Fallback: single-kernel f32 version (unexpected n or small ws) ----
__global__ __launch_bounds__(256)
void hash_embed_fallback(const float* __restrict__ x,
                         const float* __restrict__ tables,
                         float* __restrict__ out,
                         int n)
{
    const int p = blockIdx.x * 256 + threadIdx.x;
    if (p >= n) return;

    const float xn0 = (x[3 * p + 0] + 1.0f) * 0.5f;
    const float xn1 = (x[3 * p + 1] + 1.0f) * 0.5f;
    const float xn2 = (x[3 * p + 2] + 1.0f) * 0.5f;

    float o[2 * NLVL];
#pragma unroll
    for (int l = 0; l < NLVL; ++l) {
        const float2* tab = (const float2*)tables + ((size_t)l << 19);
        const float r = c_res[l];
        const float s0 = xn0 * r, s1 = xn1 * r, s2 = xn2 * r;
        const float f0 = floorf(s0), f1 = floorf(s1), f2 = floorf(s2);
        const float w0 = s0 - f0, w1 = s1 - f1, w2 = s2 - f2;
        const unsigned v0 = (unsigned)(int)f0;
        const unsigned v1 = (unsigned)(int)f1;
        const unsigned v2 = (unsigned)(int)f2;
        const unsigned bx0 = v1 * P1, bx1 = (v1 + 1u) * P1;
        const unsigned cx0 = v2 * P2, cx1 = (v2 + 1u) * P2;
        const float2 e0 = tab[(v0 ^ bx0 ^ cx0) & TMASK];
        const float2 e1 = tab[(v0 ^ bx0 ^ cx1) & TMASK];
        const float2 e2 = tab[(v0 ^ bx1 ^ cx0) & TMASK];
        const float2 e3 = tab[(v0 ^ bx1 ^ cx1) & TMASK];
        const float2 e4 = tab[((v0 + 1u) ^ bx0 ^ cx0) & TMASK];
        const float2 e5 = tab[((v0 + 1u) ^ bx0 ^ cx1) & TMASK];
        const float2 e6 = tab[((v0 + 1u) ^ bx1 ^ cx0) & TMASK];
        const float2 e7 = tab[((v0 + 1u) ^ bx1 ^ cx1) & TMASK];
        const float omx = 1.f - w0, omy = 1.f - w1, omz = 1.f - w2;
        const float c00x = e0.x * omx + e4.x * w0;
        const float c00y = e0.y * omx + e4.y * w0;
        const float c01x = e1.x * omx + e5.x * w0;
        const float c01y = e1.y * omx + e5.y * w0;
        const float c10x = e2.x * omx + e6.x * w0;
        const float c10y = e2.y * omx + e6.y * w0;
        const float c11x = e3.x * omx + e7.x * w0;
        const float c11y = e3.y * omx + e7.y * w0;
        const float c0x = c00x * omy + c10x * w1;
        const float c0y = c00y * omy + c10y * w1;
        const float c1x = c01x * omy + c11x * w1;
        const float c1y = c01y * omy + c11y * w1;
        o[2 * l + 0] = c0x * omz + c1x * w2;
        o[2 * l + 1] = c0y * omz + c1y * w2;
    }

    float4* op = (float4*)(out + (size_t)p * 32);
#pragma unroll
    for (int q = 0; q < 8; ++q)
        op[q] = make_float4(o[4 * q], o[4 * q + 1], o[4 * q + 2], o[4 * q + 3]);
}

extern "C" void kernel_launch(void* const* d_in, const int* in_sizes, int n_in,
                              void* d_out, int out_size, void* d_ws, size_t ws_size,
                              hipStream_t stream) {
    const float* x = (const float*)d_in[0];
    const float* tables = (const float*)d_in[1];
    float* out = (float*)d_out;
    const int n = in_sizes[0] / 3;                       // 1048576

    char* ws = (char*)d_ws;
    float4*   sorted_pts = (float4*)ws;                                        // 16 MB
    unsigned* counts     = (unsigned*)(ws + ((size_t)16 << 20));               // 128 KB
    unsigned* cursor     = (unsigned*)(ws + ((size_t)16 << 20) + (128 << 10)); // 128 KB
    const size_t ws_needed = ((size_t)16 << 20) + (256 << 10);

    if (n == (1 << 20) && ws_size >= ws_needed) {
        hipMemsetAsync(counts, 0, NBINS * sizeof(unsigned), stream);
        k_count<<<4096, 256, 0, stream>>>(x, counts);
        k_scan<<<1, 1024, 0, stream>>>(counts, cursor);
        k_place<<<4096, 256, 0, stream>>>(x, cursor, sorted_pts);
        k_gather_staged<<<4096, 256, 0, stream>>>(sorted_pts, tables, out);
    } else {
        hash_embed_fallback<<<(n + 255) / 256, 256, 0, stream>>>(x, tables, out, n);
    }
}